// Round 6
// baseline (69.005 us; speedup 1.0000x reference)
//
#include <hip/hip_runtime.h>
#include <math.h>

#define PX 32              // pixels per block (shared across 3 anchors)
#define NT 192             // 3 waves; wave id == anchor in transform phase
#define RAWF (270 * PX)    // raw floats staged per block: 3*90*32 = 8640 (34560 B)

__device__ __forceinline__ float sigf(float x) { return 1.0f / (1.0f + expf(-x)); }

// Phases: (1) cooperative vectorized load of raw [3][90][PX] region into LDS
// (full 64B lines, deep MLP); (2) per-(row,half) LDS-transpose read + transform
// in registers; (3) in-place row-major [96][90] write; (4) coalesced flush.
template<int H, int W, int T, bool VEC>
__device__ __forceinline__ void decode_level(
    const float* __restrict__ in, const float* __restrict__ anchors,
    float th, float invCase, float* __restrict__ out, long gRowBase,
    int blkL, float* __restrict__ lds)
{
    constexpr int HW = H * W;
    constexpr int SPANS = (HW + PX - 1) / PX;
    const int b    = blkL / SPANS;
    const int P0   = (blkL % SPANS) * PX;
    const int npix = (HW - P0 < PX) ? (HW - P0) : PX;
    const int tid  = threadIdx.x;

    const float* srcb = in + (long)b * (270LL * HW) + P0;

    // ---- phase 1: raw staging ----
    if (VEC) {
        // float4 chunks; chunk i: ch = i>>3 (a*90+c), part = i&7 (pixel group of 4).
        // HW%4==0 and P0%32==0 -> 16B aligned. Tail spans have npix in {16,4}.
        #pragma unroll
        for (int k = 0; k < 11; ++k) {          // 11*192 = 2112 full chunks
            int i = tid + k * NT;
            int part = i & 7, ch = i >> 3;
            if (part * 4 < npix) {
                float4 val = *(const float4*)(srcb + (long)ch * HW + part * 4);
                *(float4*)(&lds[i * 4]) = val;
            }
        }
        {   int i = tid + 11 * NT;              // remaining 48 chunks
            if (i < RAWF / 4) {
                int part = i & 7, ch = i >> 3;
                if (part * 4 < npix) {
                    float4 val = *(const float4*)(srcb + (long)ch * HW + part * 4);
                    *(float4*)(&lds[i * 4]) = val;
                }
            }
        }
    } else {
        // 13-level: HW=169 odd -> no 16B alignment; dword granularity.
        for (int i = tid; i < RAWF; i += NT) {
            int p = i & (PX - 1), ch = i >> 5;
            if (p < npix) lds[i] = srcb[(long)ch * HW + p];
        }
    }
    __syncthreads();

    // ---- phase 2: transpose-read + transform (thread = (pixel p, anchor a, half h)) ----
    const int a = tid >> 6, lane = tid & 63, h = lane >> 5, p = lane & 31;
    const bool act = p < npix;
    float v[45];
    if (act) {
        const float* rs = lds + (a * 90 + 45 * h) * PX + p;   // banks: 2-way, free
        #pragma unroll
        for (int j = 0; j < 45; ++j) v[j] = rs[j * PX];

        // Row scalars valid on h==0 lanes (their v[0..4] = channels 0..4).
        float sp = sigf(v[0]);
        bool  m  = sp > th;
        float A0 = anchors[a * 2 + 0], A1 = anchors[a * 2 + 1];
        float w  = A0 * expf(v[3]);
        float hb = A1 * expf(v[4]);
        float s  = sqrtf(w * w + hb * hb) * invCase;
        int pix = P0 + p;
        int x = pix % W, y = pix / W;
        float cx = ((float)x + v[1]) * (float)T;
        float cy = ((float)y + v[2]) * (float)T;

        float ms = __shfl(m ? s : 0.0f, p, 64);    // h0 -> h1 broadcast (lane p active)
        float mf = __shfl(m ? 1.0f : 0.0f, p, 64);
        const bool mB = mf > 0.5f;

        #pragma unroll
        for (int j = 0; j < 45; ++j) {
            float val = v[j];
            // k = 45h+j; coord iff k%3==0 (== j%3==0); point region k in [6,18) is
            // h==0-only, all coords scaled by s.
            bool coordAlways = (j % 3 == 0);
            bool pointRegion = (j >= 6 && j < 18);
            if (coordAlways)      v[j] = val * ms;
            else if (pointRegion) v[j] = (h == 0) ? val * ms : (mB ? sigf(val) : 0.0f);
            else                  v[j] = mB ? sigf(val) : 0.0f;
        }
        if (h == 0) {   // obj entries 0..5 (local m/s valid on h==0)
            v[0] = m ? (float)b : 0.0f;
            v[1] = m ? sp       : 0.0f;
            v[2] = m ? cx       : 0.0f;
            v[3] = m ? cy       : 0.0f;
            v[4] = m ? w        : 0.0f;
            v[5] = m ? hb       : 0.0f;
        }
    }
    __syncthreads();          // all raw reads done before overwrite

    // ---- phase 3: in-place row-major [PX*3][90] write (stride 270 ≡ 14 mod 32,
    // h-halves hit disjoint parity bank sets -> 2-way, free) ----
    if (act) {
        float* dst = lds + (p * 3 + a) * 90 + 45 * h;
        #pragma unroll
        for (int j = 0; j < 45; ++j) dst[j] = v[j];
    }
    __syncthreads();

    // ---- phase 4: coalesced flush of npix*3 contiguous rows ----
    const int nfl = npix * 3 * 90;
    const size_t gbase = (size_t)(gRowBase + ((long)b * HW + P0) * 3) * 90;
    if (VEC) {
        float4* d4 = (float4*)(out + gbase);
        const float4* s4 = (const float4*)lds;
        for (int i = tid; i < (nfl >> 2); i += NT) d4[i] = s4[i];
    } else {
        float2* d2 = (float2*)(out + gbase);
        const float2* s2 = (const float2*)lds;
        for (int i = tid; i < (nfl >> 1); i += NT) d2[i] = s2[i];
    }
}

__global__ __launch_bounds__(NT, 3) void decode_all(
    const float* __restrict__ in13, const float* __restrict__ in26,
    const float* __restrict__ in52,
    const float* __restrict__ anc13, const float* __restrict__ anc26,
    const float* __restrict__ anc52,
    const float* __restrict__ thresh, const int* __restrict__ casep,
    float* __restrict__ out, int nblk52, int nblk26, long rows13, long rows26)
{
    __shared__ float lds[RAWF];
    const float th = thresh[0];
    const float invCase = 1.0f / (float)(*casep);
    const int blk = blockIdx.x;

    if (blk < nblk52)
        decode_level<52, 52, 8, true>(in52, anc52, th, invCase, out,
                                      rows13 + rows26, blk, lds);
    else if (blk < nblk52 + nblk26)
        decode_level<26, 26, 16, true>(in26, anc26, th, invCase, out,
                                       rows13, blk - nblk52, lds);
    else
        decode_level<13, 13, 32, false>(in13, anc13, th, invCase, out,
                                        0, blk - nblk52 - nblk26, lds);
}

extern "C" void kernel_launch(void* const* d_in, const int* in_sizes, int n_in,
                              void* d_out, int out_size, void* d_ws, size_t ws_size,
                              hipStream_t stream) {
    const float* in13  = (const float*)d_in[0];
    const float* in26  = (const float*)d_in[1];
    const float* in52  = (const float*)d_in[2];
    const float* anc13 = (const float*)d_in[3];
    const float* anc26 = (const float*)d_in[4];
    const float* anc52 = (const float*)d_in[5];
    const float* th    = (const float*)d_in[6];
    const int*   casep = (const int*)d_in[7];
    float* out = (float*)d_out;

    int B = in_sizes[0] / (270 * 13 * 13);   // 32

    long rows13 = (long)B * 13 * 13 * 3;
    long rows26 = (long)B * 26 * 26 * 3;

    int nblk13 = B * ((13 * 13 + PX - 1) / PX);    // 32*6   = 192
    int nblk26 = B * ((26 * 26 + PX - 1) / PX);    // 32*22  = 704
    int nblk52 = B * ((52 * 52 + PX - 1) / PX);    // 32*85  = 2720

    decode_all<<<dim3(nblk52 + nblk26 + nblk13), dim3(NT), 0, stream>>>(
        in13, in26, in52, anc13, anc26, anc52, th, casep, out,
        nblk52, nblk26, rows13, rows26);
}

// Round 8
// 54.924 us; speedup vs baseline: 1.2564x; 1.2564x over previous
//
#include <hip/hip_runtime.h>
#include <math.h>

#define NT  192          // 3 waves; wave id == anchor
#define PXW 64           // pixels per block, wide (26/52) levels: 2 px/thread
#define PXS 32           // pixels per block, 13 level: 1 px/thread
#define FR  48           // rows per flush phase; LDS = 48*90*4 = 17280 B -> 9 blocks/CU

typedef float vf4 __attribute__((ext_vector_type(4)));
typedef float vf2 __attribute__((ext_vector_type(2)));

__device__ __forceinline__ float sigf(float x) { return 1.0f / (1.0f + expf(-x)); }

__device__ __forceinline__ void ntflush4(const float* __restrict__ lds,
                                         float* __restrict__ outp, int nfl, int tid)
{
    vf4* d4 = (vf4*)outp;
    const vf4* s4 = (const vf4*)lds;
    for (int i = tid; i < (nfl >> 2); i += NT)
        __builtin_nontemporal_store(s4[i], d4 + i);
}
__device__ __forceinline__ void ntflush2(const float* __restrict__ lds,
                                         float* __restrict__ outp, int nfl, int tid)
{
    vf2* d2 = (vf2*)outp;
    const vf2* s2 = (const vf2*)lds;
    for (int i = tid; i < (nfl >> 1); i += NT)
        __builtin_nontemporal_store(s2[i], d2 + i);
}

// Wide levels (HW even): wave a, lane = (h = lane>>5, p2 = lane&31) handles
// pixels q0=2*p2, q0+1 and entries k in [45h,45h+45) via float2 loads
// (per j the wave reads two 256B pixel-clusters = full lines).
template<int H, int W, int T>
__device__ __forceinline__ void decode_wide(
    const float* __restrict__ in, const float* __restrict__ anchors,
    float th, float invCase, float* __restrict__ out, long gRowBase,
    int blkL, float* __restrict__ lds)
{
    constexpr int HW = H * W;
    constexpr int SPANS = (HW + PXW - 1) / PXW;
    const int b    = blkL / SPANS;
    const int P0   = (blkL % SPANS) * PXW;
    const int npix = (HW - P0 < PXW) ? (HW - P0) : PXW;   // even for 26/52 tails

    const int tid = threadIdx.x;
    const int a = tid >> 6, lane = tid & 63, h = lane >> 5, p2 = lane & 31;
    const int q0 = 2 * p2;
    const bool act = q0 < npix;

    float v0[45], v1[45];
    if (act) {
        const float* src = in + ((long)b * 270 + a * 90 + 45 * h) * HW + P0 + q0;
        #pragma unroll
        for (int j = 0; j < 45; ++j) {
            vf2 t2 = *(const vf2*)(src + (long)j * HW);
            v0[j] = t2.x; v1[j] = t2.y;
        }

        // Row scalars valid on h==0 lanes (their v[0..4] = channels 0..4).
        float sp0 = sigf(v0[0]), sp1 = sigf(v1[0]);
        bool  m0 = sp0 > th,     m1 = sp1 > th;
        float A0 = anchors[a * 2 + 0], A1 = anchors[a * 2 + 1];
        float w0 = A0 * expf(v0[3]), w1 = A0 * expf(v1[3]);
        float h0 = A1 * expf(v0[4]), h1 = A1 * expf(v1[4]);
        float s0 = sqrtf(w0 * w0 + h0 * h0) * invCase;
        float s1 = sqrtf(w1 * w1 + h1 * h1) * invCase;
        int pix0 = P0 + q0;
        int x0 = pix0 % W, y0 = pix0 / W;
        int x1 = (pix0 + 1) % W, y1 = (pix0 + 1) / W;
        float cx0 = ((float)x0 + v0[1]) * (float)T, cy0 = ((float)y0 + v0[2]) * (float)T;
        float cx1 = ((float)x1 + v1[1]) * (float)T, cy1 = ((float)y1 + v1[2]) * (float)T;

        float ms0 = __shfl(m0 ? s0 : 0.0f, p2, 64);   // h0 -> h1 broadcast
        float ms1 = __shfl(m1 ? s1 : 0.0f, p2, 64);
        float mf0 = __shfl(m0 ? 1.0f : 0.0f, p2, 64);
        float mf1 = __shfl(m1 ? 1.0f : 0.0f, p2, 64);
        const bool mB0 = mf0 > 0.5f, mB1 = mf1 > 0.5f;

        #pragma unroll
        for (int j = 0; j < 45; ++j) {
            // k = 45h+j; coord iff k%3==0 (== j%3==0); point region k in [6,18)
            // exists only on h==0 and is all coords scaled by s.
            bool coord = (j % 3 == 0), pt = (j >= 6 && j < 18);
            float a0 = v0[j], a1 = v1[j];
            if (coord)   { v0[j] = a0 * ms0;  v1[j] = a1 * ms1; }
            else if (pt) { v0[j] = (h == 0) ? a0 * ms0 : (mB0 ? sigf(a0) : 0.0f);
                           v1[j] = (h == 0) ? a1 * ms1 : (mB1 ? sigf(a1) : 0.0f); }
            else         { v0[j] = mB0 ? sigf(a0) : 0.0f;
                           v1[j] = mB1 ? sigf(a1) : 0.0f; }
        }
        if (h == 0) {   // obj entries 0..5 (local m/s valid on h==0)
            v0[0] = m0 ? (float)b : 0.0f;  v1[0] = m1 ? (float)b : 0.0f;
            v0[1] = m0 ? sp0 : 0.0f;       v1[1] = m1 ? sp1 : 0.0f;
            v0[2] = m0 ? cx0 : 0.0f;       v1[2] = m1 ? cx1 : 0.0f;
            v0[3] = m0 ? cy0 : 0.0f;       v1[3] = m1 ? cy1 : 0.0f;
            v0[4] = m0 ? w0  : 0.0f;       v1[4] = m1 ? w1  : 0.0f;
            v0[5] = m0 ? h0  : 0.0f;       v1[5] = m1 ? h1  : 0.0f;
        }
    }

    const size_t gbase = (size_t)(gRowBase + ((long)b * HW + P0) * 3) * 90;
    const int myf = p2 >> 3;          // both pixels of a thread share a phase

    #pragma unroll
    for (int f = 0; f < PXW / 16; ++f) {
        int pf = npix - 16 * f;
        if (pf <= 0) break;           // block-uniform
        if (pf > 16) pf = 16;
        if (act && myf == f) {
            float* dst = lds + ((q0 - 16 * f) * 3 + a) * 90 + 45 * h;
            #pragma unroll
            for (int j = 0; j < 45; ++j) dst[j] = v0[j];
            dst += 270;
            #pragma unroll
            for (int j = 0; j < 45; ++j) dst[j] = v1[j];
        }
        __syncthreads();
        ntflush4(lds, out + gbase + (size_t)f * FR * 90, pf * 3 * 90, tid);
        __syncthreads();
    }
}

// 13-level (HW=169, odd): R5 scalar path, two-phase staging, float2 nt flush.
__device__ __forceinline__ void decode13(
    const float* __restrict__ in, const float* __restrict__ anchors,
    float th, float invCase, float* __restrict__ out,
    int blkL, float* __restrict__ lds)
{
    constexpr int H = 13, W = 13, T = 32, HW = 169;
    constexpr int SPANS = (HW + PXS - 1) / PXS;     // 6
    const int b    = blkL / SPANS;
    const int P0   = (blkL % SPANS) * PXS;
    const int npix = (HW - P0 < PXS) ? (HW - P0) : PXS;

    const int tid = threadIdx.x;
    const int a = tid >> 6, lane = tid & 63, h = lane >> 5, p = lane & 31;
    const bool act = p < npix;

    float v[45];
    if (act) {
        const int pix = P0 + p;
        const int x = pix % W, y = pix / W;
        const float* src = in + ((long)b * 270 + a * 90 + 45 * h) * HW + pix;
        #pragma unroll
        for (int j = 0; j < 45; ++j) v[j] = src[(long)j * HW];

        float sp = sigf(v[0]);
        bool  m  = sp > th;
        float A0 = anchors[a * 2 + 0], A1 = anchors[a * 2 + 1];
        float w  = A0 * expf(v[3]);
        float hb = A1 * expf(v[4]);
        float s  = sqrtf(w * w + hb * hb) * invCase;
        float cx = ((float)x + v[1]) * (float)T;
        float cy = ((float)y + v[2]) * (float)T;

        float ms = __shfl(m ? s : 0.0f, p, 64);
        float mf = __shfl(m ? 1.0f : 0.0f, p, 64);
        const bool mB = mf > 0.5f;

        #pragma unroll
        for (int j = 0; j < 45; ++j) {
            float val = v[j];
            bool coord = (j % 3 == 0), pt = (j >= 6 && j < 18);
            if (coord)   v[j] = val * ms;
            else if (pt) v[j] = (h == 0) ? val * ms : (mB ? sigf(val) : 0.0f);
            else         v[j] = mB ? sigf(val) : 0.0f;
        }
        if (h == 0) {
            v[0] = m ? (float)b : 0.0f;
            v[1] = m ? sp       : 0.0f;
            v[2] = m ? cx       : 0.0f;
            v[3] = m ? cy       : 0.0f;
            v[4] = m ? w        : 0.0f;
            v[5] = m ? hb       : 0.0f;
        }
    }

    const size_t gbase = (size_t)(((long)b * HW + P0) * 3) * 90;

    if (act && p < 16) {
        float* dst = lds + (p * 3 + a) * 90 + 45 * h;
        #pragma unroll
        for (int j = 0; j < 45; ++j) dst[j] = v[j];
    }
    __syncthreads();
    int nA = npix < 16 ? npix : 16;
    ntflush2(lds, out + gbase, nA * 3 * 90, tid);

    int nB = npix - 16;
    if (nB > 0) {
        __syncthreads();
        if (act && p >= 16) {
            float* dst = lds + ((p - 16) * 3 + a) * 90 + 45 * h;
            #pragma unroll
            for (int j = 0; j < 45; ++j) dst[j] = v[j];
        }
        __syncthreads();
        ntflush2(lds, out + gbase + (size_t)FR * 90, nB * 3 * 90, tid);
    }
}

__global__ __launch_bounds__(NT, 4) void decode_all(
    const float* __restrict__ in13, const float* __restrict__ in26,
    const float* __restrict__ in52,
    const float* __restrict__ anc13, const float* __restrict__ anc26,
    const float* __restrict__ anc52,
    const float* __restrict__ thresh, const int* __restrict__ casep,
    float* __restrict__ out, int nblk52, int nblk26, long rows13, long rows26)
{
    __shared__ float lds[FR * 90];
    const float th = thresh[0];
    const float invCase = 1.0f / (float)(*casep);
    const int blk = blockIdx.x;

    if (blk < nblk52)
        decode_wide<52, 52, 8>(in52, anc52, th, invCase, out,
                               rows13 + rows26, blk, lds);
    else if (blk < nblk52 + nblk26)
        decode_wide<26, 26, 16>(in26, anc26, th, invCase, out,
                                rows13, blk - nblk52, lds);
    else
        decode13(in13, anc13, th, invCase, out, blk - nblk52 - nblk26, lds);
}

extern "C" void kernel_launch(void* const* d_in, const int* in_sizes, int n_in,
                              void* d_out, int out_size, void* d_ws, size_t ws_size,
                              hipStream_t stream) {
    const float* in13  = (const float*)d_in[0];
    const float* in26  = (const float*)d_in[1];
    const float* in52  = (const float*)d_in[2];
    const float* anc13 = (const float*)d_in[3];
    const float* anc26 = (const float*)d_in[4];
    const float* anc52 = (const float*)d_in[5];
    const float* th    = (const float*)d_in[6];
    const int*   casep = (const int*)d_in[7];
    float* out = (float*)d_out;

    int B = in_sizes[0] / (270 * 13 * 13);   // 32

    long rows13 = (long)B * 13 * 13 * 3;
    long rows26 = (long)B * 26 * 26 * 3;

    int nblk13 = B * ((13 * 13 + PXS - 1) / PXS);   // 32*6  = 192
    int nblk26 = B * ((26 * 26 + PXW - 1) / PXW);   // 32*11 = 352
    int nblk52 = B * ((52 * 52 + PXW - 1) / PXW);   // 32*43 = 1376

    decode_all<<<dim3(nblk52 + nblk26 + nblk13), dim3(NT), 0, stream>>>(
        in13, in26, in52, anc13, anc26, anc52, th, casep, out,
        nblk52, nblk26, rows13, rows26);
}